// Round 4
// baseline (4555.742 us; speedup 1.0000x reference)
//
#include <hip/hip_runtime.h>
#include <hip/hip_bf16.h>

typedef __attribute__((ext_vector_type(8))) short bf16x8;
typedef __attribute__((ext_vector_type(4))) float f32x4;
typedef unsigned short u16;
typedef unsigned int u32;

#define BN_EPS 1e-5f

__device__ __forceinline__ float u2f_lo(u32 p) {
    u32 x = p << 16;
    float f; __builtin_memcpy(&f, &x, 4); return f;
}
__device__ __forceinline__ float u2f_hi(u32 p) {
    u32 x = p & 0xffff0000u;
    float f; __builtin_memcpy(&f, &x, 4); return f;
}
// Saturating fp32->bf16 (launders NaN/Inf -> finite; inputs are finite fp32).
__device__ __forceinline__ u16 f2b(float f) {
    f = fminf(fmaxf(f, -3.0e38f), 3.0e38f);
    __hip_bfloat16 h = __float2bfloat16(f);
    u16 s; __builtin_memcpy(&s, &h, 2); return s;
}
__device__ __forceinline__ bf16x8 cvt8(f32x4 a, f32x4 b) {
    bf16x8 r;
    r[0] = (short)f2b(a[0]); r[1] = (short)f2b(a[1]);
    r[2] = (short)f2b(a[2]); r[3] = (short)f2b(a[3]);
    r[4] = (short)f2b(b[0]); r[5] = (short)f2b(b[1]);
    r[6] = (short)f2b(b[2]); r[7] = (short)f2b(b[3]);
    return r;
}

// fp32 -> bf16 weight conversion (once per launch, into d_ws arena)
__global__ __launch_bounds__(256) void k_cvtw(const float* __restrict__ src,
                                              u16* __restrict__ dst, int n) {
    const int i = blockIdx.x * 256 + threadIdx.x;
    if (i < n) dst[i] = f2b(src[i]);
}

// ---------------------------------------------------------------------------
// MFMA GEMM core: acc += A[rel rows, K](fp32) @ W[Nout,K]^T (bf16, row-major).
// Rows >= Mload read as zero. Wave: 32 rows x 64 cols.
// A-frag A[m=lane&15][k=quad*8+j]; B-frag W[n=lane&15][k=quad*8+j];
// C/D col=lane&15, row=quad*4+reg.
// ---------------------------------------------------------------------------
__device__ __forceinline__ void gemm_acc(const float* A, int lda, int Mload,
                                         const u16* W, int K,
                                         int rowBase, int colBase,
                                         f32x4 (&acc)[2][4])
{
    const int lane = threadIdx.x & 63;
    const int r16 = lane & 15;
    const int quad = lane >> 4;
    int r0 = rowBase + r16;
    int r1 = rowBase + 16 + r16;
    const bool z0 = (r0 >= Mload), z1 = (r1 >= Mload);
    if (z0) r0 = 0;
    if (z1) r1 = 0;
    const bf16x8 zf = {0,0,0,0,0,0,0,0};
    for (int kk = 0; kk < K; kk += 32) {
        const int ko = kk + quad * 8;
        const f32x4* p0 = (const f32x4*)(A + (size_t)r0 * lda + ko);
        const f32x4* p1 = (const f32x4*)(A + (size_t)r1 * lda + ko);
        bf16x8 a0 = cvt8(p0[0], p0[1]);
        bf16x8 a1 = cvt8(p1[0], p1[1]);
        if (z0) a0 = zf;
        if (z1) a1 = zf;
#pragma unroll
        for (int nt = 0; nt < 4; ++nt) {
            const bf16x8 b = *(const bf16x8*)(W + (size_t)(colBase + nt * 16 + r16) * K + ko);
            acc[0][nt] = __builtin_amdgcn_mfma_f32_16x16x32_bf16(a0, b, acc[0][nt], 0, 0, 0);
            acc[1][nt] = __builtin_amdgcn_mfma_f32_16x16x32_bf16(a1, b, acc[1][nt], 0, 0, 0);
        }
    }
}

// ---------------------------------------------------------------------------
// Fused QKV + attention, one block per (graph, head). q/k/v via MFMA into
// 48 KiB LDS (bf16). attnOut rows relative to `lo`, fp32.
// ---------------------------------------------------------------------------
__global__ __launch_bounds__(256) void k_attn(
    const float* __restrict__ x, const u16* __restrict__ Wqkv,
    const float* __restrict__ bqkv, float* __restrict__ attnOut,
    int lo, int N)
{
    __shared__ u16 qs[256 * 32];
    __shared__ u16 ks[256 * 32];
    __shared__ u16 vs[256 * 32];
    const int brel = blockIdx.x >> 3;
    const int h = blockIdx.x & 7;
    const int base = lo + brel * 256;
    const int count = min(256, N - base);
    const int t = threadIdx.x;
    const int wave = t >> 6;
    const int lane = t & 63;
    const int r16 = lane & 15;
    const int quad = lane >> 4;

#pragma unroll
    for (int sel = 0; sel < 3; ++sel) {
        f32x4 acc[4][2] = {};
        for (int kk = 0; kk < 256; kk += 32) {
            const int ko = kk + quad * 8;
            bf16x8 a[4];
#pragma unroll
            for (int mt = 0; mt < 4; ++mt) {
                int row = base + wave * 64 + mt * 16 + r16;
                row = min(row, N - 1);          // clamp: clamped rows never used
                const f32x4* p = (const f32x4*)(x + (size_t)row * 256 + ko);
                a[mt] = cvt8(p[0], p[1]);
            }
#pragma unroll
            for (int nt = 0; nt < 2; ++nt) {
                const int wrow = sel * 256 + h * 32 + nt * 16 + r16;
                const bf16x8 b = *(const bf16x8*)(Wqkv + (size_t)wrow * 256 + ko);
#pragma unroll
                for (int mt = 0; mt < 4; ++mt)
                    acc[mt][nt] = __builtin_amdgcn_mfma_f32_16x16x32_bf16(a[mt], b, acc[mt][nt], 0, 0, 0);
            }
        }
        u16* dst = (sel == 0) ? qs : (sel == 1) ? ks : vs;
#pragma unroll
        for (int nt = 0; nt < 2; ++nt) {
            const int col = nt * 16 + r16;
            const float bias = bqkv[sel * 256 + h * 32 + col];
#pragma unroll
            for (int mt = 0; mt < 4; ++mt) {
#pragma unroll
                for (int r = 0; r < 4; ++r) {
                    const int row = wave * 64 + mt * 16 + quad * 4 + r;
                    dst[row * 32 + col] = f2b(acc[mt][nt][r] + bias);
                }
            }
        }
    }
    __syncthreads();
    if (t >= count) return;    // padded rows of last graph: no valid query

    float qreg[32];
    {
        const u32* qp = (const u32*)(qs + t * 32);
#pragma unroll
        for (int j = 0; j < 16; ++j) {
            const u32 p = qp[j];
            qreg[2 * j] = u2f_lo(p);
            qreg[2 * j + 1] = u2f_hi(p);
        }
    }
    float o[32];
#pragma unroll
    for (int d = 0; d < 32; ++d) o[d] = 0.f;
    float sum = 0.f;
    const float scale = 0.17677669529663687f;  // 1/sqrt(32)

    for (int s = 0; s < count; ++s) {
        const u32* kp = (const u32*)(ks + s * 32);  // wave-uniform: LDS broadcast
        const u32* vp = (const u32*)(vs + s * 32);
        float s0 = 0.f, s1 = 0.f, s2 = 0.f, s3 = 0.f;
#pragma unroll
        for (int j = 0; j < 16; j += 2) {
            const u32 p0 = kp[j], p1 = kp[j + 1];
            s0 = fmaf(qreg[2 * j + 0], u2f_lo(p0), s0);
            s1 = fmaf(qreg[2 * j + 1], u2f_hi(p0), s1);
            s2 = fmaf(qreg[2 * j + 2], u2f_lo(p1), s2);
            s3 = fmaf(qreg[2 * j + 3], u2f_hi(p1), s3);
        }
        float sc = ((s0 + s1) + (s2 + s3)) * scale;
        sc = fminf(fmaxf(sc, -50.f), 50.f);
        const float e = __expf(sc);
        sum += e;
#pragma unroll
        for (int j = 0; j < 16; ++j) {
            const u32 pv = vp[j];
            o[2 * j + 0] = fmaf(e, u2f_lo(pv), o[2 * j + 0]);
            o[2 * j + 1] = fmaf(e, u2f_hi(pv), o[2 * j + 1]);
        }
    }
    const float inv = 1.f / fmaxf(sum, 1e-30f);
    float* op = attnOut + ((size_t)(brel * 256 + t)) * 256 + h * 32;
#pragma unroll
    for (int j = 0; j < 8; ++j) {
        f32x4 st;
        st[0] = o[4 * j + 0] * inv; st[1] = o[4 * j + 1] * inv;
        st[2] = o[4 * j + 2] * inv; st[3] = o[4 * j + 3] * inv;
        ((f32x4*)op)[j] = st;
    }
}

// h2 = bn2(attn@Wo^T + bo + x) -> d_out rows [lo,hi)   (overwrite)
__global__ __launch_bounds__(256) void k_out2(
    const float* __restrict__ attn, const u16* __restrict__ Wo,
    const float* __restrict__ bo, const float* __restrict__ x,
    const float* __restrict__ g2, const float* __restrict__ be2,
    const float* __restrict__ m2, const float* __restrict__ v2,
    float* __restrict__ dout, int lo, int hi)
{
    const int wave = threadIdx.x >> 6;
    const int rowBase = blockIdx.y * 128 + wave * 32;
    const int colBase = blockIdx.x * 64;
    const int ML = hi - lo;
    f32x4 acc[2][4] = {};
    gemm_acc(attn, 256, ML, Wo, 256, rowBase, colBase, acc);
    const int lane = threadIdx.x & 63;
    const int r16 = lane & 15, quad = lane >> 4;
#pragma unroll
    for (int nt = 0; nt < 4; ++nt) {
        const int col = colBase + nt * 16 + r16;
        const float bias = bo[col];
        const float mm = m2[col];
        const float sc = g2[col] * rsqrtf(v2[col] + BN_EPS);
        const float bb = be2[col];
#pragma unroll
        for (int tt = 0; tt < 2; ++tt) {
#pragma unroll
            for (int r = 0; r < 4; ++r) {
                const int rel = rowBase + tt * 16 + quad * 4 + r;
                if (rel < ML) {
                    const size_t idx = (size_t)(lo + rel) * 256 + col;
                    const float val = acc[tt][nt][r] + bias + x[idx];
                    dout[idx] = (val - mm) * sc + bb;
                }
            }
        }
    }
}

// Edge scatter for dst in [lo,hi): agg[dst-lo] += x[src], fp32 atomics.
__global__ __launch_bounds__(256) void k_scatter(
    const float* __restrict__ x, const int* __restrict__ esrc,
    const int* __restrict__ edst, float* __restrict__ agg,
    int E, int lo, int hi)
{
    const int wid = (blockIdx.x << 2) + (threadIdx.x >> 6);
    if (wid >= E) return;
    const int d = edst[wid];
    if (d < lo || d >= hi) return;
    const int lane = threadIdx.x & 63;
    const int s = esrc[wid];
    const f32x4 xv = *(const f32x4*)(x + (size_t)s * 256 + lane * 4);
    float* ap = agg + (size_t)(d - lo) * 256 + lane * 4;
    atomicAdd(ap + 0, xv[0]);
    atomicAdd(ap + 1, xv[1]);
    atomicAdd(ap + 2, xv[2]);
    atomicAdd(ap + 3, xv[3]);
}

// d_out += bn1(agg@Wnei^T + x@Wroot^T + b_nei + x)   rows [lo,hi)
__global__ __launch_bounds__(256) void k_conv(
    const float* __restrict__ agg, const float* __restrict__ x,
    const u16* __restrict__ Wnei, const u16* __restrict__ Wroot,
    const float* __restrict__ bnei,
    const float* __restrict__ g1, const float* __restrict__ be1,
    const float* __restrict__ m1, const float* __restrict__ v1,
    float* __restrict__ dout, int lo, int hi)
{
    const int wave = threadIdx.x >> 6;
    const int rowBase = blockIdx.y * 128 + wave * 32;
    const int colBase = blockIdx.x * 64;
    const int ML = hi - lo;
    f32x4 acc[2][4] = {};
    gemm_acc(agg, 256, ML, Wnei, 256, rowBase, colBase, acc);
    gemm_acc(x + (size_t)lo * 256, 256, ML, Wroot, 256, rowBase, colBase, acc);
    const int lane = threadIdx.x & 63;
    const int r16 = lane & 15, quad = lane >> 4;
#pragma unroll
    for (int nt = 0; nt < 4; ++nt) {
        const int col = colBase + nt * 16 + r16;
        const float bias = bnei[col];
        const float mm = m1[col];
        const float sc = g1[col] * rsqrtf(v1[col] + BN_EPS);
        const float bb = be1[col];
#pragma unroll
        for (int tt = 0; tt < 2; ++tt) {
#pragma unroll
            for (int r = 0; r < 4; ++r) {
                const int rel = rowBase + tt * 16 + quad * 4 + r;
                if (rel < ML) {
                    const size_t idx = (size_t)(lo + rel) * 256 + col;
                    const float val = acc[tt][nt][r] + bias + x[idx];
                    dout[idx] += (val - mm) * sc + bb;
                }
            }
        }
    }
}

// Fused MLP + bn3, in place over d_out. Block = 64 rows x 256 cols.
// 4 K-stages of 128: t_s = relu(out@W1_s^T+b1_s) -> 16KiB LDS -> yacc += t_s@W2_s^T.
__global__ __launch_bounds__(256) void k_mlp(
    const u16* __restrict__ W1, const float* __restrict__ b1,
    const u16* __restrict__ W2, const float* __restrict__ b2v,
    const float* __restrict__ g3, const float* __restrict__ be3,
    const float* __restrict__ m3, const float* __restrict__ v3,
    float* __restrict__ dout, int N)
{
    __shared__ u16 ts[64 * 128];
    const int rowBase = blockIdx.x * 64;
    const int t = threadIdx.x;
    const int wave = t >> 6;
    const int lane = t & 63;
    const int r16 = lane & 15;
    const int quad = lane >> 4;

    f32x4 yacc[4][4] = {};

    for (int s = 0; s < 4; ++s) {
        f32x4 a1[4][2] = {};
        for (int kk = 0; kk < 256; kk += 32) {
            const int ko = kk + quad * 8;
            bf16x8 a[4];
#pragma unroll
            for (int mt = 0; mt < 4; ++mt) {
                int row = rowBase + mt * 16 + r16;
                row = min(row, N - 1);          // clamp stays within this block
                const f32x4* p = (const f32x4*)(dout + (size_t)row * 256 + ko);
                a[mt] = cvt8(p[0], p[1]);
            }
#pragma unroll
            for (int nt = 0; nt < 2; ++nt) {
                const int wrow = s * 128 + wave * 32 + nt * 16 + r16;
                const bf16x8 b = *(const bf16x8*)(W1 + (size_t)wrow * 256 + ko);
#pragma unroll
                for (int mt = 0; mt < 4; ++mt)
                    a1[mt][nt] = __builtin_amdgcn_mfma_f32_16x16x32_bf16(a[mt], b, a1[mt][nt], 0, 0, 0);
            }
        }
        __syncthreads();
#pragma unroll
        for (int nt = 0; nt < 2; ++nt) {
            const int col = wave * 32 + nt * 16 + r16;
            const float bias = b1[s * 128 + col];
#pragma unroll
            for (int mt = 0; mt < 4; ++mt) {
#pragma unroll
                for (int r = 0; r < 4; ++r) {
                    const int row = mt * 16 + quad * 4 + r;
                    ts[row * 128 + col] = f2b(fmaxf(a1[mt][nt][r] + bias, 0.f));
                }
            }
        }
        __syncthreads();
        for (int kk = 0; kk < 128; kk += 32) {
            const int ko = kk + quad * 8;
            bf16x8 a[4];
#pragma unroll
            for (int mt = 0; mt < 4; ++mt)
                a[mt] = *(const bf16x8*)(ts + (mt * 16 + r16) * 128 + ko);
#pragma unroll
            for (int nt = 0; nt < 4; ++nt) {
                const int wrow = wave * 64 + nt * 16 + r16;
                const bf16x8 b = *(const bf16x8*)(W2 + (size_t)wrow * 512 + s * 128 + ko);
#pragma unroll
                for (int mt = 0; mt < 4; ++mt)
                    yacc[mt][nt] = __builtin_amdgcn_mfma_f32_16x16x32_bf16(a[mt], b, yacc[mt][nt], 0, 0, 0);
            }
        }
    }
#pragma unroll
    for (int nt = 0; nt < 4; ++nt) {
        const int col = wave * 64 + nt * 16 + r16;
        const float bias = b2v[col];
        const float mm = m3[col];
        const float sc = g3[col] * rsqrtf(v3[col] + BN_EPS);
        const float bb = be3[col];
#pragma unroll
        for (int mt = 0; mt < 4; ++mt) {
#pragma unroll
            for (int r = 0; r < 4; ++r) {
                const int grow = rowBase + mt * 16 + quad * 4 + r;
                if (grow < N) {
                    const size_t idx = (size_t)grow * 256 + col;
                    const float val = yacc[mt][nt][r] + bias + dout[idx];
                    dout[idx] = (val - mm) * sc + bb;
                }
            }
        }
    }
}

extern "C" void kernel_launch(void* const* d_in, const int* in_sizes, int n_in,
                              void* d_out, int out_size, void* d_ws, size_t ws_size,
                              hipStream_t stream)
{
    (void)n_in; (void)out_size;
    const int N = in_sizes[0] / 256;
    const int E = in_sizes[1] / 2;

    const float* x     = (const float*)d_in[0];
    const int*   ei    = (const int*)d_in[1];
    const float* Wroot = (const float*)d_in[3];
    const float* Wnei  = (const float*)d_in[4];
    const float* bnei  = (const float*)d_in[5];
    const float* Wqkv  = (const float*)d_in[6];
    const float* bqkv  = (const float*)d_in[7];
    const float* Wo    = (const float*)d_in[8];
    const float* bo    = (const float*)d_in[9];
    const float* W1    = (const float*)d_in[10];
    const float* b1    = (const float*)d_in[11];
    const float* W2    = (const float*)d_in[12];
    const float* b2    = (const float*)d_in[13];
    const float* g1 = (const float*)d_in[14], *be1 = (const float*)d_in[15];
    const float* m1 = (const float*)d_in[16], *v1  = (const float*)d_in[17];
    const float* g2 = (const float*)d_in[18], *be2 = (const float*)d_in[19];
    const float* m2 = (const float*)d_in[20], *v2  = (const float*)d_in[21];
    const float* g3 = (const float*)d_in[22], *be3 = (const float*)d_in[23];
    const float* m3 = (const float*)d_in[24], *v3  = (const float*)d_in[25];
    float* dout = (float*)d_out;

    // --- d_ws layout ---
    // [0, 2 MiB): bf16 weight arena (Wroot|Wnei|Wqkv|Wo|W1|W2)
    // [2 MiB, ...): chunk arena: agg fp32 / attn fp32, chunkRows x 1024 B
    u16* wb = (u16*)d_ws;
    u16* Wroot_b = wb;                 // 65536
    u16* Wnei_b  = wb + 65536;         // 65536
    u16* Wqkv_b  = wb + 131072;        // 196608
    u16* Wo_b    = wb + 327680;        // 65536
    u16* W1_b    = wb + 393216;        // 131072
    u16* W2_b    = wb + 524288;        // 131072  (total 655360 elems, 1.25 MiB)
    const size_t WB_BYTES = 2u << 20;

    k_cvtw<<<dim3(256),  256, 0, stream>>>(Wroot, Wroot_b, 65536);
    k_cvtw<<<dim3(256),  256, 0, stream>>>(Wnei,  Wnei_b,  65536);
    k_cvtw<<<dim3(768),  256, 0, stream>>>(Wqkv,  Wqkv_b,  196608);
    k_cvtw<<<dim3(256),  256, 0, stream>>>(Wo,    Wo_b,    65536);
    k_cvtw<<<dim3(512),  256, 0, stream>>>(W1,    W1_b,    131072);
    k_cvtw<<<dim3(512),  256, 0, stream>>>(W2,    W2_b,    131072);

    size_t arena = (ws_size > WB_BYTES) ? (ws_size - WB_BYTES) : 0;
    size_t maxRows = arena / 1024;     // fp32 row = 1024 B (agg and attn alike)
    int chunkRows = (int)((maxRows < 65536 ? maxRows : 65536) & ~(size_t)255);
    if (chunkRows < 256) chunkRows = 256;

    float* agg  = (float*)((char*)d_ws + WB_BYTES);
    float* attn = agg;                 // phases don't overlap

    // Phase A: h2 branch -> d_out (overwrite; chunked by graphs)
    for (int lo = 0; lo < N; lo += chunkRows) {
        const int hi = min(lo + chunkRows, N);
        const int ngraph = (hi - lo + 255) / 256;
        k_attn<<<dim3(ngraph * 8), 256, 0, stream>>>(x, Wqkv_b, bqkv, attn, lo, N);
        k_out2<<<dim3(4, (hi - lo + 127) / 128), 256, 0, stream>>>(
            attn, Wo_b, bo, x, g2, be2, m2, v2, dout, lo, hi);
    }
    // Phase B: conv branch accumulated into d_out (chunked by nodes)
    for (int lo = 0; lo < N; lo += chunkRows) {
        const int hi = min(lo + chunkRows, N);
        hipMemsetAsync(agg, 0, (size_t)(hi - lo) * 1024, stream);
        k_scatter<<<dim3((E + 3) / 4), 256, 0, stream>>>(x, ei, ei + E, agg, E, lo, hi);
        k_conv<<<dim3(4, (hi - lo + 127) / 128), 256, 0, stream>>>(
            agg, x, Wnei_b, Wroot_b, bnei, g1, be1, m1, v1, dout, lo, hi);
    }
    // Phase C: fused MLP + bn3, in place
    k_mlp<<<dim3((N + 63) / 64), 256, 0, stream>>>(
        W1_b, b1, W2_b, b2, g3, be3, m3, v3, dout, N);
}

// Round 5
// 1460.909 us; speedup vs baseline: 3.1184x; 3.1184x over previous
//
#include <hip/hip_runtime.h>
#include <hip/hip_bf16.h>

typedef __attribute__((ext_vector_type(8))) short bf16x8;
typedef __attribute__((ext_vector_type(4))) float f32x4;
typedef unsigned short u16;
typedef unsigned int u32;

#define BN_EPS 1e-5f
#define NBINS 65536

__device__ __forceinline__ float u2f_lo(u32 p) {
    u32 x = p << 16;
    float f; __builtin_memcpy(&f, &x, 4); return f;
}
__device__ __forceinline__ float u2f_hi(u32 p) {
    u32 x = p & 0xffff0000u;
    float f; __builtin_memcpy(&f, &x, 4); return f;
}
__device__ __forceinline__ u16 f2b(float f) {
    f = fminf(fmaxf(f, -3.0e38f), 3.0e38f);
    __hip_bfloat16 h = __float2bfloat16(f);
    u16 s; __builtin_memcpy(&s, &h, 2); return s;
}
__device__ __forceinline__ bf16x8 cvt8(f32x4 a, f32x4 b) {
    bf16x8 r;
    r[0] = (short)f2b(a[0]); r[1] = (short)f2b(a[1]);
    r[2] = (short)f2b(a[2]); r[3] = (short)f2b(a[3]);
    r[4] = (short)f2b(b[0]); r[5] = (short)f2b(b[1]);
    r[6] = (short)f2b(b[2]); r[7] = (short)f2b(b[3]);
    return r;
}

// fp32 -> bf16 weight conversion (once per launch, into d_ws arena)
__global__ __launch_bounds__(256) void k_cvtw(const float* __restrict__ src,
                                              u16* __restrict__ dst, int n) {
    const int i = blockIdx.x * 256 + threadIdx.x;
    if (i < n) dst[i] = f2b(src[i]);
}

// ---------------------------------------------------------------------------
// CSR build: hist -> scan -> reorder (counting sort of edges by dst)
// ---------------------------------------------------------------------------
__global__ __launch_bounds__(256) void k_hist(
    const int* __restrict__ edst, int* __restrict__ counts, int E) {
    const int i = blockIdx.x * 256 + threadIdx.x;
    if (i < E) atomicAdd(&counts[edst[i]], 1);
}

__global__ __launch_bounds__(1024) void k_scan(
    const int* __restrict__ counts, int* __restrict__ start,
    int* __restrict__ cursor) {
    __shared__ int sums[1024];
    const int t = threadIdx.x;
    const int base = t * 64;
    int s = 0;
#pragma unroll 8
    for (int j = 0; j < 64; ++j) s += counts[base + j];
    sums[t] = s;
    __syncthreads();
    for (int off = 1; off < 1024; off <<= 1) {
        const int tmp = (t >= off) ? sums[t - off] : 0;
        __syncthreads();
        sums[t] += tmp;
        __syncthreads();
    }
    int run = sums[t] - s;          // exclusive prefix for this thread's chunk
    for (int j = 0; j < 64; ++j) {
        start[base + j] = run;
        cursor[base + j] = run;
        run += counts[base + j];
    }
    if (t == 1023) start[NBINS] = run;
}

__global__ __launch_bounds__(256) void k_reorder(
    const int* __restrict__ esrc, const int* __restrict__ edst,
    int* __restrict__ cursor, int* __restrict__ ssrc, int E) {
    const int i = blockIdx.x * 256 + threadIdx.x;
    if (i < E) {
        const int p = atomicAdd(&cursor[edst[i]], 1);
        ssrc[p] = esrc[i];
    }
}

// One wave per dst row: register-accumulate all sources, single write.
__global__ __launch_bounds__(256) void k_aggregate(
    const float* __restrict__ x, const int* __restrict__ ssrc,
    const int* __restrict__ start, float* __restrict__ agg,
    int lo, int hi) {
    const int rel = (blockIdx.x << 2) + (threadIdx.x >> 6);
    const int r = lo + rel;
    if (r >= hi) return;
    const int lane = threadIdx.x & 63;
    const int s0 = start[r], s1 = start[r + 1];
    f32x4 acc = {0.f, 0.f, 0.f, 0.f};
    int j = s0;
    int sNext = (j < s1) ? ssrc[j] : 0;
    while (j < s1) {
        const int s = sNext;
        ++j;
        if (j < s1) sNext = ssrc[j];
        const f32x4 xv = *(const f32x4*)(x + (size_t)s * 256 + lane * 4);
        acc[0] += xv[0]; acc[1] += xv[1]; acc[2] += xv[2]; acc[3] += xv[3];
    }
    *(f32x4*)(agg + (size_t)rel * 256 + lane * 4) = acc;
}

// ---------------------------------------------------------------------------
// MFMA GEMM core: acc += A[rel rows, K](fp32) @ W[Nout,K]^T (bf16, row-major).
// Rows >= Mload read as zero. Wave: 32 rows x 64 cols.
// ---------------------------------------------------------------------------
__device__ __forceinline__ void gemm_acc(const float* A, int lda, int Mload,
                                         const u16* W, int K,
                                         int rowBase, int colBase,
                                         f32x4 (&acc)[2][4])
{
    const int lane = threadIdx.x & 63;
    const int r16 = lane & 15;
    const int quad = lane >> 4;
    int r0 = rowBase + r16;
    int r1 = rowBase + 16 + r16;
    const bool z0 = (r0 >= Mload), z1 = (r1 >= Mload);
    if (z0) r0 = 0;
    if (z1) r1 = 0;
    const bf16x8 zf = {0,0,0,0,0,0,0,0};
    for (int kk = 0; kk < K; kk += 32) {
        const int ko = kk + quad * 8;
        const f32x4* p0 = (const f32x4*)(A + (size_t)r0 * lda + ko);
        const f32x4* p1 = (const f32x4*)(A + (size_t)r1 * lda + ko);
        bf16x8 a0 = cvt8(p0[0], p0[1]);
        bf16x8 a1 = cvt8(p1[0], p1[1]);
        if (z0) a0 = zf;
        if (z1) a1 = zf;
#pragma unroll
        for (int nt = 0; nt < 4; ++nt) {
            const bf16x8 b = *(const bf16x8*)(W + (size_t)(colBase + nt * 16 + r16) * K + ko);
            acc[0][nt] = __builtin_amdgcn_mfma_f32_16x16x32_bf16(a0, b, acc[0][nt], 0, 0, 0);
            acc[1][nt] = __builtin_amdgcn_mfma_f32_16x16x32_bf16(a1, b, acc[1][nt], 0, 0, 0);
        }
    }
}

// ---------------------------------------------------------------------------
// Fused QKV + attention, one block per (graph, head).
// ---------------------------------------------------------------------------
__global__ __launch_bounds__(256) void k_attn(
    const float* __restrict__ x, const u16* __restrict__ Wqkv,
    const float* __restrict__ bqkv, float* __restrict__ attnOut,
    int lo, int N)
{
    __shared__ u16 qs[256 * 32];
    __shared__ u16 ks[256 * 32];
    __shared__ u16 vs[256 * 32];
    const int brel = blockIdx.x >> 3;
    const int h = blockIdx.x & 7;
    const int base = lo + brel * 256;
    const int count = min(256, N - base);
    const int t = threadIdx.x;
    const int wave = t >> 6;
    const int lane = t & 63;
    const int r16 = lane & 15;
    const int quad = lane >> 4;

#pragma unroll
    for (int sel = 0; sel < 3; ++sel) {
        f32x4 acc[4][2] = {};
        for (int kk = 0; kk < 256; kk += 32) {
            const int ko = kk + quad * 8;
            bf16x8 a[4];
#pragma unroll
            for (int mt = 0; mt < 4; ++mt) {
                int row = base + wave * 64 + mt * 16 + r16;
                row = min(row, N - 1);
                const f32x4* p = (const f32x4*)(x + (size_t)row * 256 + ko);
                a[mt] = cvt8(p[0], p[1]);
            }
#pragma unroll
            for (int nt = 0; nt < 2; ++nt) {
                const int wrow = sel * 256 + h * 32 + nt * 16 + r16;
                const bf16x8 b = *(const bf16x8*)(Wqkv + (size_t)wrow * 256 + ko);
#pragma unroll
                for (int mt = 0; mt < 4; ++mt)
                    acc[mt][nt] = __builtin_amdgcn_mfma_f32_16x16x32_bf16(a[mt], b, acc[mt][nt], 0, 0, 0);
            }
        }
        u16* dst = (sel == 0) ? qs : (sel == 1) ? ks : vs;
#pragma unroll
        for (int nt = 0; nt < 2; ++nt) {
            const int col = nt * 16 + r16;
            const float bias = bqkv[sel * 256 + h * 32 + col];
#pragma unroll
            for (int mt = 0; mt < 4; ++mt) {
#pragma unroll
                for (int r = 0; r < 4; ++r) {
                    const int row = wave * 64 + mt * 16 + quad * 4 + r;
                    dst[row * 32 + col] = f2b(acc[mt][nt][r] + bias);
                }
            }
        }
    }
    __syncthreads();
    if (t >= count) return;

    float qreg[32];
    {
        const u32* qp = (const u32*)(qs + t * 32);
#pragma unroll
        for (int j = 0; j < 16; ++j) {
            const u32 p = qp[j];
            qreg[2 * j] = u2f_lo(p);
            qreg[2 * j + 1] = u2f_hi(p);
        }
    }
    float o[32];
#pragma unroll
    for (int d = 0; d < 32; ++d) o[d] = 0.f;
    float sum = 0.f;
    const float scale = 0.17677669529663687f;  // 1/sqrt(32)

    for (int s = 0; s < count; ++s) {
        const u32* kp = (const u32*)(ks + s * 32);
        const u32* vp = (const u32*)(vs + s * 32);
        float s0 = 0.f, s1 = 0.f, s2 = 0.f, s3 = 0.f;
#pragma unroll
        for (int j = 0; j < 16; j += 2) {
            const u32 p0 = kp[j], p1 = kp[j + 1];
            s0 = fmaf(qreg[2 * j + 0], u2f_lo(p0), s0);
            s1 = fmaf(qreg[2 * j + 1], u2f_hi(p0), s1);
            s2 = fmaf(qreg[2 * j + 2], u2f_lo(p1), s2);
            s3 = fmaf(qreg[2 * j + 3], u2f_hi(p1), s3);
        }
        float sc = ((s0 + s1) + (s2 + s3)) * scale;
        sc = fminf(fmaxf(sc, -50.f), 50.f);
        const float e = __expf(sc);
        sum += e;
#pragma unroll
        for (int j = 0; j < 16; ++j) {
            const u32 pv = vp[j];
            o[2 * j + 0] = fmaf(e, u2f_lo(pv), o[2 * j + 0]);
            o[2 * j + 1] = fmaf(e, u2f_hi(pv), o[2 * j + 1]);
        }
    }
    const float inv = 1.f / fmaxf(sum, 1e-30f);
    float* op = attnOut + ((size_t)(brel * 256 + t)) * 256 + h * 32;
#pragma unroll
    for (int j = 0; j < 8; ++j) {
        f32x4 st;
        st[0] = o[4 * j + 0] * inv; st[1] = o[4 * j + 1] * inv;
        st[2] = o[4 * j + 2] * inv; st[3] = o[4 * j + 3] * inv;
        ((f32x4*)op)[j] = st;
    }
}

// h2 = bn2(attn@Wo^T + bo + x) -> d_out rows [lo,hi)   (overwrite)
__global__ __launch_bounds__(256) void k_out2(
    const float* __restrict__ attn, const u16* __restrict__ Wo,
    const float* __restrict__ bo, const float* __restrict__ x,
    const float* __restrict__ g2, const float* __restrict__ be2,
    const float* __restrict__ m2, const float* __restrict__ v2,
    float* __restrict__ dout, int lo, int hi)
{
    const int wave = threadIdx.x >> 6;
    const int rowBase = blockIdx.y * 128 + wave * 32;
    const int colBase = blockIdx.x * 64;
    const int ML = hi - lo;
    f32x4 acc[2][4] = {};
    gemm_acc(attn, 256, ML, Wo, 256, rowBase, colBase, acc);
    const int lane = threadIdx.x & 63;
    const int r16 = lane & 15, quad = lane >> 4;
#pragma unroll
    for (int nt = 0; nt < 4; ++nt) {
        const int col = colBase + nt * 16 + r16;
        const float bias = bo[col];
        const float mm = m2[col];
        const float sc = g2[col] * rsqrtf(v2[col] + BN_EPS);
        const float bb = be2[col];
#pragma unroll
        for (int tt = 0; tt < 2; ++tt) {
#pragma unroll
            for (int r = 0; r < 4; ++r) {
                const int rel = rowBase + tt * 16 + quad * 4 + r;
                if (rel < ML) {
                    const size_t idx = (size_t)(lo + rel) * 256 + col;
                    const float val = acc[tt][nt][r] + bias + x[idx];
                    dout[idx] = (val - mm) * sc + bb;
                }
            }
        }
    }
}

// d_out += bn1(agg@Wnei^T + x@Wroot^T + b_nei + x)   rows [lo,hi)
__global__ __launch_bounds__(256) void k_conv(
    const float* __restrict__ agg, const float* __restrict__ x,
    const u16* __restrict__ Wnei, const u16* __restrict__ Wroot,
    const float* __restrict__ bnei,
    const float* __restrict__ g1, const float* __restrict__ be1,
    const float* __restrict__ m1, const float* __restrict__ v1,
    float* __restrict__ dout, int lo, int hi)
{
    const int wave = threadIdx.x >> 6;
    const int rowBase = blockIdx.y * 128 + wave * 32;
    const int colBase = blockIdx.x * 64;
    const int ML = hi - lo;
    f32x4 acc[2][4] = {};
    gemm_acc(agg, 256, ML, Wnei, 256, rowBase, colBase, acc);
    gemm_acc(x + (size_t)lo * 256, 256, ML, Wroot, 256, rowBase, colBase, acc);
    const int lane = threadIdx.x & 63;
    const int r16 = lane & 15, quad = lane >> 4;
#pragma unroll
    for (int nt = 0; nt < 4; ++nt) {
        const int col = colBase + nt * 16 + r16;
        const float bias = bnei[col];
        const float mm = m1[col];
        const float sc = g1[col] * rsqrtf(v1[col] + BN_EPS);
        const float bb = be1[col];
#pragma unroll
        for (int tt = 0; tt < 2; ++tt) {
#pragma unroll
            for (int r = 0; r < 4; ++r) {
                const int rel = rowBase + tt * 16 + quad * 4 + r;
                if (rel < ML) {
                    const size_t idx = (size_t)(lo + rel) * 256 + col;
                    const float val = acc[tt][nt][r] + bias + x[idx];
                    dout[idx] += (val - mm) * sc + bb;
                }
            }
        }
    }
}

// Fused MLP + bn3, in place over d_out.
__global__ __launch_bounds__(256) void k_mlp(
    const u16* __restrict__ W1, const float* __restrict__ b1,
    const u16* __restrict__ W2, const float* __restrict__ b2v,
    const float* __restrict__ g3, const float* __restrict__ be3,
    const float* __restrict__ m3, const float* __restrict__ v3,
    float* __restrict__ dout, int N)
{
    __shared__ u16 ts[64 * 128];
    const int rowBase = blockIdx.x * 64;
    const int t = threadIdx.x;
    const int wave = t >> 6;
    const int lane = t & 63;
    const int r16 = lane & 15;
    const int quad = lane >> 4;

    f32x4 yacc[4][4] = {};

    for (int s = 0; s < 4; ++s) {
        f32x4 a1[4][2] = {};
        for (int kk = 0; kk < 256; kk += 32) {
            const int ko = kk + quad * 8;
            bf16x8 a[4];
#pragma unroll
            for (int mt = 0; mt < 4; ++mt) {
                int row = rowBase + mt * 16 + r16;
                row = min(row, N - 1);
                const f32x4* p = (const f32x4*)(dout + (size_t)row * 256 + ko);
                a[mt] = cvt8(p[0], p[1]);
            }
#pragma unroll
            for (int nt = 0; nt < 2; ++nt) {
                const int wrow = s * 128 + wave * 32 + nt * 16 + r16;
                const bf16x8 b = *(const bf16x8*)(W1 + (size_t)wrow * 256 + ko);
#pragma unroll
                for (int mt = 0; mt < 4; ++mt)
                    a1[mt][nt] = __builtin_amdgcn_mfma_f32_16x16x32_bf16(a[mt], b, a1[mt][nt], 0, 0, 0);
            }
        }
        __syncthreads();
#pragma unroll
        for (int nt = 0; nt < 2; ++nt) {
            const int col = wave * 32 + nt * 16 + r16;
            const float bias = b1[s * 128 + col];
#pragma unroll
            for (int mt = 0; mt < 4; ++mt) {
#pragma unroll
                for (int r = 0; r < 4; ++r) {
                    const int row = mt * 16 + quad * 4 + r;
                    ts[row * 128 + col] = f2b(fmaxf(a1[mt][nt][r] + bias, 0.f));
                }
            }
        }
        __syncthreads();
        for (int kk = 0; kk < 128; kk += 32) {
            const int ko = kk + quad * 8;
            bf16x8 a[4];
#pragma unroll
            for (int mt = 0; mt < 4; ++mt)
                a[mt] = *(const bf16x8*)(ts + (mt * 16 + r16) * 128 + ko);
#pragma unroll
            for (int nt = 0; nt < 4; ++nt) {
                const int wrow = wave * 64 + nt * 16 + r16;
                const bf16x8 b = *(const bf16x8*)(W2 + (size_t)wrow * 512 + s * 128 + ko);
#pragma unroll
                for (int mt = 0; mt < 4; ++mt)
                    yacc[mt][nt] = __builtin_amdgcn_mfma_f32_16x16x32_bf16(a[mt], b, yacc[mt][nt], 0, 0, 0);
            }
        }
    }
#pragma unroll
    for (int nt = 0; nt < 4; ++nt) {
        const int col = wave * 64 + nt * 16 + r16;
        const float bias = b2v[col];
        const float mm = m3[col];
        const float sc = g3[col] * rsqrtf(v3[col] + BN_EPS);
        const float bb = be3[col];
#pragma unroll
        for (int mt = 0; mt < 4; ++mt) {
#pragma unroll
            for (int r = 0; r < 4; ++r) {
                const int grow = rowBase + mt * 16 + quad * 4 + r;
                if (grow < N) {
                    const size_t idx = (size_t)grow * 256 + col;
                    const float val = yacc[mt][nt][r] + bias + dout[idx];
                    dout[idx] = (val - mm) * sc + bb;
                }
            }
        }
    }
}

extern "C" void kernel_launch(void* const* d_in, const int* in_sizes, int n_in,
                              void* d_out, int out_size, void* d_ws, size_t ws_size,
                              hipStream_t stream)
{
    (void)n_in; (void)out_size;
    const int N = in_sizes[0] / 256;
    const int E = in_sizes[1] / 2;

    const float* x     = (const float*)d_in[0];
    const int*   ei    = (const int*)d_in[1];
    const float* Wroot = (const float*)d_in[3];
    const float* Wnei  = (const float*)d_in[4];
    const float* bnei  = (const float*)d_in[5];
    const float* Wqkv  = (const float*)d_in[6];
    const float* bqkv  = (const float*)d_in[7];
    const float* Wo    = (const float*)d_in[8];
    const float* bo    = (const float*)d_in[9];
    const float* W1    = (const float*)d_in[10];
    const float* b1    = (const float*)d_in[11];
    const float* W2    = (const float*)d_in[12];
    const float* b2    = (const float*)d_in[13];
    const float* g1 = (const float*)d_in[14], *be1 = (const float*)d_in[15];
    const float* m1 = (const float*)d_in[16], *v1  = (const float*)d_in[17];
    const float* g2 = (const float*)d_in[18], *be2 = (const float*)d_in[19];
    const float* m2 = (const float*)d_in[20], *v2  = (const float*)d_in[21];
    const float* g3 = (const float*)d_in[22], *be3 = (const float*)d_in[23];
    const float* m3 = (const float*)d_in[24], *v3  = (const float*)d_in[25];
    float* dout = (float*)d_out;

    // --- d_ws layout ---
    // [0, 2 MiB)        bf16 weight arena
    // [2 MiB, +786KB)   CSR meta: counts[65536] | start[65537] | cursor[65537]
    // [3 MiB, +4 MiB)   sorted src indices (E ints)
    // [7 MiB, ...)      chunk arena: agg fp32 / attn fp32 (chunkRows x 1024 B)
    u16* wb = (u16*)d_ws;
    u16* Wroot_b = wb;
    u16* Wnei_b  = wb + 65536;
    u16* Wqkv_b  = wb + 131072;
    u16* Wo_b    = wb + 327680;
    u16* W1_b    = wb + 393216;
    u16* W2_b    = wb + 524288;
    const size_t WB_BYTES   = 2u << 20;
    const size_t META_BYTES = 1u << 20;
    const size_t SORT_BYTES = 4u << 20;
    const size_t FIXED = WB_BYTES + META_BYTES + SORT_BYTES;   // 7 MiB

    int* meta   = (int*)((char*)d_ws + WB_BYTES);
    int* counts = meta;
    int* start  = meta + NBINS;
    int* cursor = start + NBINS + 1;
    int* ssrc   = (int*)((char*)d_ws + WB_BYTES + META_BYTES);

    k_cvtw<<<dim3(256),  256, 0, stream>>>(Wroot, Wroot_b, 65536);
    k_cvtw<<<dim3(256),  256, 0, stream>>>(Wnei,  Wnei_b,  65536);
    k_cvtw<<<dim3(768),  256, 0, stream>>>(Wqkv,  Wqkv_b,  196608);
    k_cvtw<<<dim3(256),  256, 0, stream>>>(Wo,    Wo_b,    65536);
    k_cvtw<<<dim3(512),  256, 0, stream>>>(W1,    W1_b,    131072);
    k_cvtw<<<dim3(512),  256, 0, stream>>>(W2,    W2_b,    131072);

    size_t arena = (ws_size > FIXED) ? (ws_size - FIXED) : 0;
    size_t maxRows = arena / 1024;
    int chunkRows = (int)((maxRows < 65536 ? maxRows : 65536) & ~(size_t)255);
    if (chunkRows < 256) chunkRows = 256;

    float* agg  = (float*)((char*)d_ws + FIXED);
    float* attn = agg;                 // phases don't overlap

    // CSR build (once, covers all dst)
    hipMemsetAsync(counts, 0, NBINS * 4, stream);
    k_hist   <<<dim3((E + 255) / 256), 256, 0, stream>>>(ei + E, counts, E);
    k_scan   <<<dim3(1), 1024, 0, stream>>>(counts, start, cursor);
    k_reorder<<<dim3((E + 255) / 256), 256, 0, stream>>>(ei, ei + E, cursor, ssrc, E);

    // Phase A: h2 branch -> d_out (overwrite; chunked by graphs)
    for (int lo = 0; lo < N; lo += chunkRows) {
        const int hi = min(lo + chunkRows, N);
        const int ngraph = (hi - lo + 255) / 256;
        k_attn<<<dim3(ngraph * 8), 256, 0, stream>>>(x, Wqkv_b, bqkv, attn, lo, N);
        k_out2<<<dim3(4, (hi - lo + 127) / 128), 256, 0, stream>>>(
            attn, Wo_b, bo, x, g2, be2, m2, v2, dout, lo, hi);
    }
    // Phase B: conv branch accumulated into d_out (chunked by nodes)
    for (int lo = 0; lo < N; lo += chunkRows) {
        const int hi = min(lo + chunkRows, N);
        k_aggregate<<<dim3((hi - lo + 3) / 4), 256, 0, stream>>>(x, ssrc, start, agg, lo, hi);
        k_conv<<<dim3(4, (hi - lo + 127) / 128), 256, 0, stream>>>(
            agg, x, Wnei_b, Wroot_b, bnei, g1, be1, m1, v1, dout, lo, hi);
    }
    // Phase C: fused MLP + bn3, in place
    k_mlp<<<dim3((N + 63) / 64), 256, 0, stream>>>(
        W1_b, b1, W2_b, b2, g3, be3, m3, v3, dout, N);
}

// Round 6
// 988.425 us; speedup vs baseline: 4.6091x; 1.4780x over previous
//
#include <hip/hip_runtime.h>
#include <hip/hip_bf16.h>

typedef __attribute__((ext_vector_type(8))) short bf16x8;
typedef __attribute__((ext_vector_type(4))) float f32x4;
typedef unsigned short u16;
typedef unsigned int u32;

#define BN_EPS 1e-5f
#define NBINS 65536

__device__ __forceinline__ float b2f(u16 u) {
    u32 x = ((u32)u) << 16;
    float f; __builtin_memcpy(&f, &x, 4); return f;
}
__device__ __forceinline__ u16 f2b(float f) {
    f = fminf(fmaxf(f, -3.0e38f), 3.0e38f);
    __hip_bfloat16 h = __float2bfloat16(f);
    u16 s; __builtin_memcpy(&s, &h, 2); return s;
}
__device__ __forceinline__ bf16x8 cvt8(f32x4 a, f32x4 b) {
    bf16x8 r;
    r[0] = (short)f2b(a[0]); r[1] = (short)f2b(a[1]);
    r[2] = (short)f2b(a[2]); r[3] = (short)f2b(a[3]);
    r[4] = (short)f2b(b[0]); r[5] = (short)f2b(b[1]);
    r[6] = (short)f2b(b[2]); r[7] = (short)f2b(b[3]);
    return r;
}
#define MFMA(a, b, c) __builtin_amdgcn_mfma_f32_16x16x32_bf16((a), (b), (c), 0, 0, 0)

// fp32 -> bf16 conversions (once per launch, into d_ws arena)
__global__ __launch_bounds__(256) void k_cvtw(const float* __restrict__ src,
                                              u16* __restrict__ dst, int n) {
    const int i = blockIdx.x * 256 + threadIdx.x;
    if (i < n) dst[i] = f2b(src[i]);
}
__global__ __launch_bounds__(256) void k_cvtx(const float* __restrict__ src,
                                              u16* __restrict__ dst, int n4) {
    const int i = blockIdx.x * 256 + threadIdx.x;
    if (i < n4) {
        const f32x4 v = ((const f32x4*)src)[i];
        ushort4 pk;
        pk.x = f2b(v[0]); pk.y = f2b(v[1]); pk.z = f2b(v[2]); pk.w = f2b(v[3]);
        ((ushort4*)dst)[i] = pk;
    }
}

// ---------------------------------------------------------------------------
// CSR build: hist -> scan -> reorder (counting sort of edges by dst)
// ---------------------------------------------------------------------------
__global__ __launch_bounds__(256) void k_hist(
    const int* __restrict__ edst, int* __restrict__ counts, int E) {
    const int i = blockIdx.x * 256 + threadIdx.x;
    if (i < E) atomicAdd(&counts[edst[i]], 1);
}

__global__ __launch_bounds__(1024) void k_scan(
    const int* __restrict__ counts, int* __restrict__ start,
    int* __restrict__ cursor) {
    __shared__ int sums[1024];
    const int t = threadIdx.x;
    const int base = t * 64;
    int s = 0;
#pragma unroll 8
    for (int j = 0; j < 64; ++j) s += counts[base + j];
    sums[t] = s;
    __syncthreads();
    for (int off = 1; off < 1024; off <<= 1) {
        const int tmp = (t >= off) ? sums[t - off] : 0;
        __syncthreads();
        sums[t] += tmp;
        __syncthreads();
    }
    int run = sums[t] - s;
    for (int j = 0; j < 64; ++j) {
        start[base + j] = run;
        cursor[base + j] = run;
        run += counts[base + j];
    }
    if (t == 1023) start[NBINS] = run;
}

__global__ __launch_bounds__(256) void k_reorder(
    const int* __restrict__ esrc, const int* __restrict__ edst,
    int* __restrict__ cursor, int* __restrict__ ssrc, int E) {
    const int i = blockIdx.x * 256 + threadIdx.x;
    if (i < E) {
        const int p = atomicAdd(&cursor[edst[i]], 1);
        ssrc[p] = esrc[i];
    }
}

// One wave per dst row: register-accumulate (fp32) from bf16 x, bf16 row out.
__global__ __launch_bounds__(256) void k_aggregate(
    const u16* __restrict__ xb, const int* __restrict__ ssrc,
    const int* __restrict__ start, u16* __restrict__ agg,
    int lo, int hi) {
    const int rel = (blockIdx.x << 2) + (threadIdx.x >> 6);
    const int r = lo + rel;
    if (r >= hi) return;
    const int lane = threadIdx.x & 63;
    const int s0 = start[r], s1 = start[r + 1];
    f32x4 acc = {0.f, 0.f, 0.f, 0.f};
    int j = s0;
    int sNext = (j < s1) ? ssrc[j] : 0;
    while (j < s1) {
        const int s = sNext;
        ++j;
        if (j < s1) sNext = ssrc[j];
        const ushort4 xv = *(const ushort4*)(xb + (size_t)s * 256 + lane * 4);
        acc[0] += b2f(xv.x); acc[1] += b2f(xv.y);
        acc[2] += b2f(xv.z); acc[3] += b2f(xv.w);
    }
    ushort4 pk;
    pk.x = f2b(acc[0]); pk.y = f2b(acc[1]); pk.z = f2b(acc[2]); pk.w = f2b(acc[3]);
    *(ushort4*)(agg + (size_t)rel * 256 + lane * 4) = pk;
}

// ---------------------------------------------------------------------------
// MFMA GEMM core: acc += A[rel rows, K] @ W[Nout,K]^T (W bf16 row-major).
// ABF16: A is bf16 (direct b128 loads); else fp32 with in-register cvt.
// Rows >= Mload read as zero. Wave: 32 rows x 64 cols.
// A-frag A[m=lane&15][k=quad*8+j]; B-frag W[n=lane&15][k=quad*8+j];
// C/D col=lane&15, row=quad*4+reg.
// ---------------------------------------------------------------------------
template<bool ABF16>
__device__ __forceinline__ void gemm_acc(const void* A, int lda, int Mload,
                                         const u16* W, int K,
                                         int rowBase, int colBase,
                                         f32x4 (&acc)[2][4])
{
    const int lane = threadIdx.x & 63;
    const int r16 = lane & 15;
    const int quad = lane >> 4;
    int r0 = rowBase + r16;
    int r1 = rowBase + 16 + r16;
    const bool z0 = (r0 >= Mload), z1 = (r1 >= Mload);
    if (z0) r0 = 0;
    if (z1) r1 = 0;
    const bf16x8 zf = {0,0,0,0,0,0,0,0};
    for (int kk = 0; kk < K; kk += 32) {
        const int ko = kk + quad * 8;
        bf16x8 a0, a1;
        if (ABF16) {
            const u16* Ab = (const u16*)A;
            a0 = *(const bf16x8*)(Ab + (size_t)r0 * lda + ko);
            a1 = *(const bf16x8*)(Ab + (size_t)r1 * lda + ko);
        } else {
            const float* Af = (const float*)A;
            const f32x4* p0 = (const f32x4*)(Af + (size_t)r0 * lda + ko);
            const f32x4* p1 = (const f32x4*)(Af + (size_t)r1 * lda + ko);
            a0 = cvt8(p0[0], p0[1]);
            a1 = cvt8(p1[0], p1[1]);
        }
        if (z0) a0 = zf;
        if (z1) a1 = zf;
#pragma unroll
        for (int nt = 0; nt < 4; ++nt) {
            const bf16x8 b = *(const bf16x8*)(W + (size_t)(colBase + nt * 16 + r16) * K + ko);
            acc[0][nt] = MFMA(a0, b, acc[0][nt]);
            acc[1][nt] = MFMA(a1, b, acc[1][nt]);
        }
    }
}

// ---------------------------------------------------------------------------
// MFMA flash attention, one block per (graph, head).
// Phase 1: q/k/v = xb @ W slice, via MFMA. q -> A-frag regs (LDS transpose),
//   k -> ks (stride 40), v -> vt transposed (stride 264).
// Phase 2: per 32-query m-pair, loop 8 key-blocks of 32:
//   S = q.kT (MFMA) -> exp (masked) -> P to per-wave LDS -> O += P@V (MFMA).
// No max-subtraction (scores tiny; clamp +-60 for NaN-proofing).
// ---------------------------------------------------------------------------
__global__ __launch_bounds__(256) void k_attn(
    const u16* __restrict__ xb, const u16* __restrict__ Wqkv,
    const float* __restrict__ bqkv, u16* __restrict__ attnOut,
    int lo, int N)
{
    __shared__ u16 ks_s[256 * 40];   // K: [key][d], stride 40 (2-way banks, 16B-aligned rows)
    __shared__ u16 vt_s[32 * 264];   // V^T: [d][key], stride 264
    __shared__ u16 sc_s[4 * 2560];   // per-wave scratch: q-transpose / P tiles (stride 40)
    const int brel = blockIdx.x >> 3;
    const int h = blockIdx.x & 7;
    const int base = lo + brel * 256;
    const int count = min(256, N - base);
    const int t = threadIdx.x;
    const int wave = t >> 6;
    const int lane = t & 63;
    const int r16 = lane & 15;
    const int quad = lane >> 4;
    u16* msc = sc_s + wave * 2560;
    const float scale = 0.17677669529663687f;  // 1/sqrt(32)

    bf16x8 qa[4];   // A-frags covering this wave's 64 query rows

    // ---- phase 1: projections ----
#pragma unroll
    for (int sel = 0; sel < 3; ++sel) {
        f32x4 acc[4][2] = {};
        for (int kk = 0; kk < 256; kk += 32) {
            const int ko = kk + quad * 8;
            bf16x8 a[4];
#pragma unroll
            for (int mt = 0; mt < 4; ++mt) {
                int row = base + wave * 64 + mt * 16 + r16;
                row = min(row, N - 1);   // clamped rows produce unused outputs
                a[mt] = *(const bf16x8*)(xb + (size_t)row * 256 + ko);
            }
#pragma unroll
            for (int nt = 0; nt < 2; ++nt) {
                const int wrow = sel * 256 + h * 32 + nt * 16 + r16;
                const bf16x8 b = *(const bf16x8*)(Wqkv + (size_t)wrow * 256 + ko);
#pragma unroll
                for (int mt = 0; mt < 4; ++mt)
                    acc[mt][nt] = MFMA(a[mt], b, acc[mt][nt]);
            }
        }
        if (sel == 0) {
            // q (pre-scaled) -> scratch, then A-frag readback (in-wave dep)
#pragma unroll
            for (int nt = 0; nt < 2; ++nt) {
                const float bias = bqkv[h * 32 + nt * 16 + r16];
#pragma unroll
                for (int mt = 0; mt < 4; ++mt)
#pragma unroll
                    for (int r = 0; r < 4; ++r)
                        msc[(mt * 16 + quad * 4 + r) * 40 + nt * 16 + r16] =
                            f2b((acc[mt][nt][r] + bias) * scale);
            }
#pragma unroll
            for (int mt = 0; mt < 4; ++mt)
                qa[mt] = *(const bf16x8*)(msc + (mt * 16 + r16) * 40 + quad * 8);
        } else if (sel == 1) {
#pragma unroll
            for (int nt = 0; nt < 2; ++nt) {
                const float bias = bqkv[256 + h * 32 + nt * 16 + r16];
#pragma unroll
                for (int mt = 0; mt < 4; ++mt)
#pragma unroll
                    for (int r = 0; r < 4; ++r) {
                        const int key = wave * 64 + mt * 16 + quad * 4 + r;
                        ks_s[key * 40 + nt * 16 + r16] = f2b(acc[mt][nt][r] + bias);
                    }
            }
        } else {
#pragma unroll
            for (int nt = 0; nt < 2; ++nt) {
                const int d = nt * 16 + r16;
                const float bias = bqkv[512 + h * 32 + d];
#pragma unroll
                for (int mt = 0; mt < 4; ++mt) {
                    const int key0 = wave * 64 + mt * 16 + quad * 4;
                    ushort4 pk;
                    pk.x = f2b(acc[mt][nt][0] + bias);
                    pk.y = f2b(acc[mt][nt][1] + bias);
                    pk.z = f2b(acc[mt][nt][2] + bias);
                    pk.w = f2b(acc[mt][nt][3] + bias);
                    *(ushort4*)(vt_s + d * 264 + key0) = pk;
                }
            }
        }
    }
    __syncthreads();

    // ---- phase 2: flash over key-blocks ----
#pragma unroll
    for (int mp = 0; mp < 2; ++mp) {
        f32x4 O[2][2] = {};
        f32x4 rs[2] = {};
        for (int kb = 0; kb < 8; ++kb) {
            bf16x8 bk[2];
#pragma unroll
            for (int nt = 0; nt < 2; ++nt)
                bk[nt] = *(const bf16x8*)(ks_s + (kb * 32 + nt * 16 + r16) * 40 + quad * 8);
            f32x4 S[2][2] = {};
#pragma unroll
            for (int mt = 0; mt < 2; ++mt)
#pragma unroll
                for (int nt = 0; nt < 2; ++nt)
                    S[mt][nt] = MFMA(qa[mp * 2 + mt], bk[nt], S[mt][nt]);
            // exp + key mask + rowsum + P -> scratch
#pragma unroll
            for (int mt = 0; mt < 2; ++mt)
#pragma unroll
                for (int nt = 0; nt < 2; ++nt) {
                    const int key = kb * 32 + nt * 16 + r16;
                    const bool kv = (key < count);
#pragma unroll
                    for (int r = 0; r < 4; ++r) {
                        const float s = fminf(fmaxf(S[mt][nt][r], -60.f), 60.f);
                        const float e = kv ? __expf(s) : 0.f;
                        rs[mt][r] += e;
                        msc[(mt * 16 + quad * 4 + r) * 40 + nt * 16 + r16] = f2b(e);
                    }
                }
            bf16x8 ap[2], bv[2];
#pragma unroll
            for (int mt = 0; mt < 2; ++mt)
                ap[mt] = *(const bf16x8*)(msc + (mt * 16 + r16) * 40 + quad * 8);
#pragma unroll
            for (int nt = 0; nt < 2; ++nt)
                bv[nt] = *(const bf16x8*)(vt_s + (nt * 16 + r16) * 264 + kb * 32 + quad * 8);
#pragma unroll
            for (int mt = 0; mt < 2; ++mt)
#pragma unroll
                for (int nt = 0; nt < 2; ++nt)
                    O[mt][nt] = MFMA(ap[mt], bv[nt], O[mt][nt]);
        }
        // rowsum: reduce over the 16 col-lanes (same quad group)
#pragma unroll
        for (int mt = 0; mt < 2; ++mt)
#pragma unroll
            for (int r = 0; r < 4; ++r) {
                float v = rs[mt][r];
                v += __shfl_xor(v, 1, 16);
                v += __shfl_xor(v, 2, 16);
                v += __shfl_xor(v, 4, 16);
                v += __shfl_xor(v, 8, 16);
                rs[mt][r] = v;
            }
#pragma unroll
        for (int mt = 0; mt < 2; ++mt) {
#pragma unroll
            for (int nt = 0; nt < 2; ++nt)
#pragma unroll
                for (int r = 0; r < 4; ++r) {
                    const float inv = 1.f / fmaxf(rs[mt][r], 1e-30f);
                    const int qrow = wave * 64 + mp * 32 + mt * 16 + quad * 4 + r;
                    attnOut[(size_t)(brel * 256 + qrow) * 256 + h * 32 + nt * 16 + r16]
                        = f2b(O[mt][nt][r] * inv);
                }
        }
    }
}

// h2 = bn2(attn@Wo^T + bo + x) -> d_out rows [lo,hi)   (overwrite)
__global__ __launch_bounds__(256) void k_out2(
    const u16* __restrict__ attn, const u16* __restrict__ Wo,
    const float* __restrict__ bo, const float* __restrict__ x,
    const float* __restrict__ g2, const float* __restrict__ be2,
    const float* __restrict__ m2, const float* __restrict__ v2,
    float* __restrict__ dout, int lo, int hi)
{
    const int wave = threadIdx.x >> 6;
    const int rowBase = blockIdx.y * 128 + wave * 32;
    const int colBase = blockIdx.x * 64;
    const int ML = hi - lo;
    f32x4 acc[2][4] = {};
    gemm_acc<true>(attn, 256, ML, Wo, 256, rowBase, colBase, acc);
    const int lane = threadIdx.x & 63;
    const int r16 = lane & 15, quad = lane >> 4;
#pragma unroll
    for (int nt = 0; nt < 4; ++nt) {
        const int col = colBase + nt * 16 + r16;
        const float bias = bo[col];
        const float mm = m2[col];
        const float sc = g2[col] * rsqrtf(v2[col] + BN_EPS);
        const float bb = be2[col];
#pragma unroll
        for (int tt = 0; tt < 2; ++tt) {
#pragma unroll
            for (int r = 0; r < 4; ++r) {
                const int rel = rowBase + tt * 16 + quad * 4 + r;
                if (rel < ML) {
                    const size_t idx = (size_t)(lo + rel) * 256 + col;
                    const float val = acc[tt][nt][r] + bias + x[idx];
                    dout[idx] = (val - mm) * sc + bb;
                }
            }
        }
    }
}

// d_out += bn1(agg@Wnei^T + x@Wroot^T + b_nei + x)   rows [lo,hi)
__global__ __launch_bounds__(256) void k_conv(
    const u16* __restrict__ agg, const u16* __restrict__ xb,
    const float* __restrict__ x,
    const u16* __restrict__ Wnei, const u16* __restrict__ Wroot,
    const float* __restrict__ bnei,
    const float* __restrict__ g1, const float* __restrict__ be1,
    const float* __restrict__ m1, const float* __restrict__ v1,
    float* __restrict__ dout, int lo, int hi)
{
    const int wave = threadIdx.x >> 6;
    const int rowBase = blockIdx.y * 128 + wave * 32;
    const int colBase = blockIdx.x * 64;
    const int ML = hi - lo;
    f32x4 acc[2][4] = {};
    gemm_acc<true>(agg, 256, ML, Wnei, 256, rowBase, colBase, acc);
    gemm_acc<true>(xb + (size_t)lo * 256, 256, ML, Wroot, 256, rowBase, colBase, acc);
    const int lane = threadIdx.x & 63;
    const int r16 = lane & 15, quad = lane >> 4;
#pragma unroll
    for (int nt = 0; nt < 4; ++nt) {
        const int col = colBase + nt * 16 + r16;
        const float bias = bnei[col];
        const float mm = m1[col];
        const float sc = g1[col] * rsqrtf(v1[col] + BN_EPS);
        const float bb = be1[col];
#pragma unroll
        for (int tt = 0; tt < 2; ++tt) {
#pragma unroll
            for (int r = 0; r < 4; ++r) {
                const int rel = rowBase + tt * 16 + quad * 4 + r;
                if (rel < ML) {
                    const size_t idx = (size_t)(lo + rel) * 256 + col;
                    const float val = acc[tt][nt][r] + bias + x[idx];
                    dout[idx] += (val - mm) * sc + bb;
                }
            }
        }
    }
}

// Fused MLP + bn3, in place over d_out.
__global__ __launch_bounds__(256) void k_mlp(
    const u16* __restrict__ W1, const float* __restrict__ b1,
    const u16* __restrict__ W2, const float* __restrict__ b2v,
    const float* __restrict__ g3, const float* __restrict__ be3,
    const float* __restrict__ m3, const float* __restrict__ v3,
    float* __restrict__ dout, int N)
{
    __shared__ u16 ts[64 * 128];
    const int rowBase = blockIdx.x * 64;
    const int t = threadIdx.x;
    const int wave = t >> 6;
    const int lane = t & 63;
    const int r16 = lane & 15;
    const int quad = lane >> 4;

    f32x4 yacc[4][4] = {};

    for (int s = 0; s < 4; ++s) {
        f32x4 a1[4][2] = {};
        for (int kk = 0; kk < 256; kk += 32) {
            const int ko = kk + quad * 8;
            bf16x8 a[4];
#pragma unroll
            for (int mt = 0; mt < 4; ++mt) {
                int row = rowBase + mt * 16 + r16;
                row = min(row, N - 1);
                const f32x4* p = (const f32x4*)(dout + (size_t)row * 256 + ko);
                a[mt] = cvt8(p[0], p[1]);
            }
#pragma unroll
            for (int nt = 0; nt < 2; ++nt) {
                const int wrow = s * 128 + wave * 32 + nt * 16 + r16;
                const bf16x8 b = *(const bf16x8*)(W1 + (size_t)wrow * 256 + ko);
#pragma unroll
                for (int mt = 0; mt < 4; ++mt)
                    a1[mt][nt] = MFMA(a[mt], b, a1[mt][nt]);
            }
        }
        __syncthreads();
#pragma unroll
        for (int nt = 0; nt < 2; ++nt) {
            const int col = wave * 32 + nt * 16 + r16;
            const float bias = b1[s * 128 + col];
#pragma unroll
            for (int mt = 0; mt < 4; ++mt) {
#pragma unroll
                for (int r = 0; r < 4; ++r) {
                    const int row = mt * 16 + quad * 4 + r;
                    ts[row * 128 + col] = f2b(fmaxf(a1[mt][nt][r] + bias, 0.f));
                }
            }
        }
        __syncthreads();
        for (int kk = 0; kk < 128; kk += 32) {
            const int ko = kk + quad * 8;
            bf16x8 a[4];
#pragma unroll
            for (int mt = 0; mt < 4; ++mt)
                a[mt] = *(const bf16x8*)(ts + (mt * 16 + r16) * 128 + ko);
#pragma unroll
            for (int nt = 0; nt < 4; ++nt) {
                const int wrow = wave * 64 + nt * 16 + r16;
                const bf16x8 b = *(const bf16x8*)(W2 + (size_t)wrow * 512 + s * 128 + ko);
#pragma unroll
                for (int mt = 0; mt < 4; ++mt)
                    yacc[mt][nt] = MFMA(a[mt], b, yacc[mt][nt]);
            }
        }
    }
#pragma unroll
    for (int nt = 0; nt < 4; ++nt) {
        const int col = wave * 64 + nt * 16 + r16;
        const float bias = b2v[col];
        const float mm = m3[col];
        const float sc = g3[col] * rsqrtf(v3[col] + BN_EPS);
        const float bb = be3[col];
#pragma unroll
        for (int mt = 0; mt < 4; ++mt) {
#pragma unroll
            for (int r = 0; r < 4; ++r) {
                const int grow = rowBase + mt * 16 + quad * 4 + r;
                if (grow < N) {
                    const size_t idx = (size_t)grow * 256 + col;
                    const float val = yacc[mt][nt][r] + bias + dout[idx];
                    dout[idx] = (val - mm) * sc + bb;
                }
            }
        }
    }
}

extern "C" void kernel_launch(void* const* d_in, const int* in_sizes, int n_in,
                              void* d_out, int out_size, void* d_ws, size_t ws_size,
                              hipStream_t stream)
{
    (void)n_in; (void)out_size;
    const int N = in_sizes[0] / 256;
    const int E = in_sizes[1] / 2;

    const float* x     = (const float*)d_in[0];
    const int*   ei    = (const int*)d_in[1];
    const float* Wroot = (const float*)d_in[3];
    const float* Wnei  = (const float*)d_in[4];
    const float* bnei  = (const float*)d_in[5];
    const float* Wqkv  = (const float*)d_in[6];
    const float* bqkv  = (const float*)d_in[7];
    const float* Wo    = (const float*)d_in[8];
    const float* bo    = (const float*)d_in[9];
    const float* W1    = (const float*)d_in[10];
    const float* b1    = (const float*)d_in[11];
    const float* W2    = (const float*)d_in[12];
    const float* b2    = (const float*)d_in[13];
    const float* g1 = (const float*)d_in[14], *be1 = (const float*)d_in[15];
    const float* m1 = (const float*)d_in[16], *v1  = (const float*)d_in[17];
    const float* g2 = (const float*)d_in[18], *be2 = (const float*)d_in[19];
    const float* m2 = (const float*)d_in[20], *v2  = (const float*)d_in[21];
    const float* g3 = (const float*)d_in[22], *be3 = (const float*)d_in[23];
    const float* m3 = (const float*)d_in[24], *v3  = (const float*)d_in[25];
    float* dout = (float*)d_out;

    // --- d_ws layout ---
    // [0, 2 MiB)     bf16 weight arena
    // [2, 3 MiB)     CSR meta: counts[65536] | start[65537] | cursor[65537]
    // [3, 7 MiB)     sorted src indices (E ints)
    // [7, 39 MiB)    xb: x as bf16 (65536 x 256)
    // [39 MiB, ...)  chunk arena: agg bf16 / attn bf16 (chunkRows x 512 B)
    u16* wb = (u16*)d_ws;
    u16* Wroot_b = wb;
    u16* Wnei_b  = wb + 65536;
    u16* Wqkv_b  = wb + 131072;
    u16* Wo_b    = wb + 327680;
    u16* W1_b    = wb + 393216;
    u16* W2_b    = wb + 524288;
    const size_t WB_BYTES   = 2u << 20;
    const size_t META_BYTES = 1u << 20;
    const size_t SORT_BYTES = 4u << 20;
    const size_t XB_BYTES   = 32u << 20;
    const size_t FIXED = WB_BYTES + META_BYTES + SORT_BYTES + XB_BYTES;  // 39 MiB

    int* meta   = (int*)((char*)d_ws + WB_BYTES);
    int* counts = meta;
    int* start  = meta + NBINS;
    int* cursor = start + NBINS + 1;
    int* ssrc   = (int*)((char*)d_ws + WB_BYTES + META_BYTES);
    u16* xb     = (u16*)((char*)d_ws + WB_BYTES + META_BYTES + SORT_BYTES);

    k_cvtw<<<dim3(256),  256, 0, stream>>>(Wroot, Wroot_b, 65536);
    k_cvtw<<<dim3(256),  256, 0, stream>>>(Wnei,  Wnei_b,  65536);
    k_cvtw<<<dim3(768),  256, 0, stream>>>(Wqkv,  Wqkv_b,  196608);
    k_cvtw<<<dim3(256),  256, 0, stream>>>(Wo,    Wo_b,    65536);
    k_cvtw<<<dim3(512),  256, 0, stream>>>(W1,    W1_b,    131072);
    k_cvtw<<<dim3(512),  256, 0, stream>>>(W2,    W2_b,    131072);
    const int n4 = (N * 256) / 4;
    k_cvtx<<<dim3((n4 + 255) / 256), 256, 0, stream>>>(x, xb, n4);

    size_t arena = (ws_size > FIXED) ? (ws_size - FIXED) : 0;
    size_t maxRows = arena / 512;      // bf16 row = 512 B (agg and attn alike)
    int chunkRows = (int)((maxRows < 65536 ? maxRows : 65536) & ~(size_t)255);
    if (chunkRows < 256) chunkRows = 256;

    u16* agg  = (u16*)((char*)d_ws + FIXED);
    u16* attn = agg;                   // phases don't overlap

    // CSR build (once, covers all dst)
    hipMemsetAsync(counts, 0, NBINS * 4, stream);
    k_hist   <<<dim3((E + 255) / 256), 256, 0, stream>>>(ei + E, counts, E);
    k_scan   <<<dim3(1), 1024, 0, stream>>>(counts, start, cursor);
    k_reorder<<<dim3((E + 255) / 256), 256, 0, stream>>>(ei, ei + E, cursor, ssrc, E);

    // Phase A: h2 branch -> d_out (overwrite; chunked by graphs)
    for (int lo = 0; lo < N; lo += chunkRows) {
        const int hi = min(lo + chunkRows, N);
        const int ngraph = (hi - lo + 255) / 256;
        k_attn<<<dim3(ngraph * 8), 256, 0, stream>>>(xb, Wqkv_b, bqkv, attn, lo, N);
        k_out2<<<dim3(4, (hi - lo + 127) / 128), 256, 0, stream>>>(
            attn, Wo_b, bo, x, g2, be2, m2, v2, dout, lo, hi);
    }
    // Phase B: conv branch accumulated into d_out (chunked by nodes)
    for (int lo = 0; lo < N; lo += chunkRows) {
        const int hi = min(lo + chunkRows, N);
        k_aggregate<<<dim3((hi - lo + 3) / 4), 256, 0, stream>>>(xb, ssrc, start, agg, lo, hi);
        k_conv<<<dim3(4, (hi - lo + 127) / 128), 256, 0, stream>>>(
            agg, xb, x, Wnei_b, Wroot_b, bnei, g1, be1, m1, v1, dout, lo, hi);
    }
    // Phase C: fused MLP + bn3, in place
    k_mlp<<<dim3((N + 63) / 64), 256, 0, stream>>>(
        W1_b, b1, W2_b, b2, g3, be3, m3, v3, dout, N);
}